// Round 9
// baseline (500.468 us; speedup 1.0000x reference)
//
#include <hip/hip_runtime.h>
#include <hip/hip_bf16.h>

#define NS 512
#define NV 32000
#define NB 16
#define NT 128

#ifndef __has_builtin
#define __has_builtin(x) 0
#endif

typedef int v8i __attribute__((ext_vector_type(8)));
typedef float v4f __attribute__((ext_vector_type(4)));

// ---------------------------------------------------------------------------
// e4m3fn (OCP) encode, x >= 0.
// ---------------------------------------------------------------------------
__device__ inline unsigned enc_e4m3(float x) {
    x = fminf(x, 448.0f);
    unsigned u = __float_as_uint(x);
    if (x < 0.015625f) {
        return (unsigned)(int)rintf(x * 512.0f);
    }
    unsigned u2 = u + 0x7FFFFu + ((u >> 20) & 1u);
    return (((u2 >> 23) - 120u) << 3) | ((u2 >> 20) & 7u);
}

__device__ inline unsigned pack4_e4m3(float a, float b, float c, float d) {
#if __has_builtin(__builtin_amdgcn_cvt_pk_fp8_f32)
    int v = __builtin_amdgcn_cvt_pk_fp8_f32(a, b, 0, false);
    v = __builtin_amdgcn_cvt_pk_fp8_f32(c, d, v, true);
    return (unsigned)v;
#else
    return enc_e4m3(a) | (enc_e4m3(b) << 8) | (enc_e4m3(c) << 16) | (enc_e4m3(d) << 24);
#endif
}

// low byte only (bytes 1-3 zero): one cvt_pk instead of two.
__device__ inline unsigned pack1_e4m3(float a) {
#if __has_builtin(__builtin_amdgcn_cvt_pk_fp8_f32)
    return (unsigned)__builtin_amdgcn_cvt_pk_fp8_f32(a, 0.f, 0, false) & 0xFFFFu;
#else
    return enc_e4m3(a);
#endif
}

// DPP all-lane butterfly reduce within each row of 16 lanes.
#define DPPMAX(x, ctrl) \
    x = fmaxf(x, __int_as_float(__builtin_amdgcn_mov_dpp(__float_as_int(x), ctrl, 0xF, 0xF, true)))
#define DPPADD(x, ctrl) \
    x = x + __int_as_float(__builtin_amdgcn_mov_dpp(__float_as_int(x), ctrl, 0xF, 0xF, true))

#define UMX(a, b) ((a) > (b) ? (a) : (b))

__device__ inline unsigned bytemax8(unsigned a, unsigned b) {
    unsigned m0 = UMX(a & 255u, b & 255u);
    unsigned m1 = UMX((a >> 8) & 255u, (b >> 8) & 255u);
    unsigned m2 = UMX((a >> 16) & 255u, (b >> 16) & 255u);
    unsigned m3 = UMX(a >> 24, b >> 24);
    return UMX(UMX(m0, m1), UMX(m2, m3));
}

// ---------------------------------------------------------------------------
// K1: per-state vocab logsumexp denominator only:
//   invZs[s] = (1 / sum_v exp(em[s][v])) * 2^-18
// Reduction order kept VERBATIM from the old k_emtok_T (bit-identical scale).
// The gather/transpose/store of the old pipeline is gone -- k_scan gathers
// em[s][id] directly (L3-resident).
// ---------------------------------------------------------------------------
__global__ __launch_bounds__(256) void k_logz(
    const float* __restrict__ em, float* __restrict__ invZs)
{
    const int s   = blockIdx.x;
    const int tid = threadIdx.x;
    const float* row = em + (size_t)s * NV;

    float sum = 0.f;
    const float4* row4 = (const float4*)row;
#pragma unroll 4
    for (int i = 0; i < 31; ++i) {
        float4 v = row4[tid + 256 * i];
        sum += __expf(v.x) + __expf(v.y) + __expf(v.z) + __expf(v.w);
    }
    sum += __expf(row[31744 + tid]);

#pragma unroll
    for (int off = 32; off; off >>= 1) sum += __shfl_down(sum, off);
    __shared__ float red[4];
    if ((tid & 63) == 0) red[tid >> 6] = sum;
    __syncthreads();
    if (tid == 0)
        invZs[s] = (1.0f / ((red[0] + red[1]) + (red[2] + red[3]))) * 0x1p-18f;
}

// ---------------------------------------------------------------------------
// K2 (fused k_z + k_pt2): per 64-row stripe of tm, compute row softmax
// denominators then PT[d][k] = exp(tm[k][d]) * 1024/rowsum_k, e4m3 fp8.
// ---------------------------------------------------------------------------
__global__ __launch_bounds__(256) void k_pt2f(
    const float* __restrict__ tm, unsigned char* __restrict__ PT)
{
    __shared__ float tile[64][65];
    __shared__ float zs[64];
    __shared__ float part[64][4];
    const int kb  = blockIdx.x * 64;
    const int tid = threadIdx.x;

    // ---- phase 1: zs[r] = 1024 / sum_d exp(tm[kb+r][d]) ----
    {
        const int r = tid >> 2, q = tid & 3;
        const float4* rp = (const float4*)(tm + (size_t)(kb + r) * NS + q * 128);
        float s = 0.f;
#pragma unroll 8
        for (int i = 0; i < 32; ++i) {
            float4 v = rp[i];
            s += (__expf(v.x) + __expf(v.y)) + (__expf(v.z) + __expf(v.w));
        }
        part[r][q] = s;
    }
    __syncthreads();
    if (tid < 64)
        zs[tid] = 1024.0f / ((part[tid][0] + part[tid][1]) + (part[tid][2] + part[tid][3]));
    __syncthreads();

    // ---- phase 2: transpose+quantize, looped over d-blocks ----
    const int c  = tid & 63;
    const int r0 = tid >> 6;
    const int d  = tid >> 2;
    const int ks = (tid & 3) * 16;
    for (int db = 0; db < NS; db += 64) {
#pragma unroll
        for (int i = 0; i < 16; ++i) {
            int r = r0 + 4 * i;
            tile[r][c] = tm[(size_t)(kb + r) * NS + db + c];
        }
        __syncthreads();
        unsigned px[4];
#pragma unroll
        for (int gq = 0; gq < 4; ++gq) {
            int k0 = ks + gq * 4;
            px[gq] = pack4_e4m3(__expf(tile[k0 + 0][d]) * zs[k0 + 0],
                                __expf(tile[k0 + 1][d]) * zs[k0 + 1],
                                __expf(tile[k0 + 2][d]) * zs[k0 + 2],
                                __expf(tile[k0 + 3][d]) * zs[k0 + 3]);
        }
        uint4 o; o.x = px[0]; o.y = px[1]; o.z = px[2]; o.w = px[3];
        *(uint4*)(PT + (size_t)(db + d) * NS + kb + ks) = o;
        __syncthreads();
    }
}

// ---------------------------------------------------------------------------
// K3 v13: direct-gather scan (no em_lin intermediate).
//   Per step each thread gathers its 4 raw em[s][id_t] values directly
//   (prefetch depth 1: gathers for step t+1 issued at the top of step t's
//   post-barrier phase -> a full ~2400-cyc latency cover; ids prefetched 2
//   ahead).  Emission = __expf(g) * invZs[s] -- bit-identical to the old
//   em_lin values.  Consumer uses the FRESH per-lane byte-max scheme (v5,
//   the fastest measured k_scan) with the v10/v11 trimmings kept: masked
//   zero-row LDS traffic, pack1, scale-reads-first, pairwise MFMA chains,
//   single barrier per step.
// ---------------------------------------------------------------------------
__global__ __launch_bounds__(512, 2) void k_scan(
    const float* __restrict__ em, const int* __restrict__ ids,
    const float* __restrict__ invZs, const unsigned char* __restrict__ PT,
    const float* __restrict__ p, float* __restrict__ out)
{
    const int bb  = blockIdx.x;        // batch group: global batches bb*4+0..3
    const int tid = threadIdx.x;
    const int w   = tid >> 6;          // wave 0..7
    const int l   = tid & 63;          // lane
    const int lc  = l & 15;            // state-col within 16-tile
    const int lq  = l >> 4;            // local batch 0..3

    __shared__ __align__(16) unsigned Ew[2][16 * 128];   // 16 KB, double-buffered
    __shared__ __align__(4) unsigned char wmE2[2][32];   // [buf][h*16 + b*4 + kt]
    __shared__ float    wm2[8][4];
    __shared__ float    sbuf[4];

    // ---- load B fragments (P, once) ----
    v8i B[4][4];
#pragma unroll
    for (int nt = 0; nt < 4; ++nt) {
#pragma unroll
        for (int kt = 0; kt < 4; ++kt) {
            const uint4* src = (const uint4*)(PT + (size_t)((w * 4 + nt) * 16 + lc) * NS + kt * 128 + lq * 32);
            v8i bb8;
            *(uint4*)&bb8       = src[0];
            *((uint4*)&bb8 + 1) = src[1];
            B[nt][kt] = bb8;
        }
    }

    // ---- zero both Ew buffers ONCE (zero rows are never rewritten) ----
    {
        uint4 zz; zz.x = 0; zz.y = 0; zz.z = 0; zz.w = 0;
        uint4* z = (uint4*)&Ew[0][0];
        z[tid * 2]     = zz;
        z[tid * 2 + 1] = zz;
    }

    // ---- prior softmax denominator ----
    float zp = 0.f;
#pragma unroll
    for (int i = 0; i < 8; ++i) zp += __expf(p[l * 8 + i]);
    DPPADD(zp, 0x128); DPPADD(zp, 0x124); DPPADD(zp, 0xB1); DPPADD(zp, 0x4E);
    float Zp = __int_as_float(__builtin_amdgcn_readlane(__float_as_int(zp), 0))
             + __int_as_float(__builtin_amdgcn_readlane(__float_as_int(zp), 16))
             + __int_as_float(__builtin_amdgcn_readlane(__float_as_int(zp), 32))
             + __int_as_float(__builtin_amdgcn_readlane(__float_as_int(zp), 48));
    const float invZp = 1.0f / Zp;

    const int dbase0 = w * 64 + lc;          // state d for nt: dbase0 + 16*nt
    const int gb     = bb * 4 + lq;          // global batch of this thread

    // ---- t-invariant gather state ----
    const int* idp = ids + gb * NT;
    const float* er[4];
    float iz[4];
#pragma unroll
    for (int nt = 0; nt < 4; ++nt) {
        er[nt] = em + (size_t)(dbase0 + 16 * nt) * NV;
        iz[nt] = invZs[dbase0 + 16 * nt];
    }

    // ---- alpha_0 (linear; 2^-18 embedded in invZs -> shift starts at 18) ----
    float alpha[4];
    {
        const int id0 = idp[0];
#pragma unroll
        for (int nt = 0; nt < 4; ++nt)
            alpha[nt] = __expf(p[dbase0 + 16 * nt]) * invZp * (__expf(er[nt][id0]) * iz[nt]);
    }

    int gsum = 18;
    const unsigned sel1 = (l & 1) ? 0x07030501u : 0x02060004u;
    const unsigned sel2 = (l & 2) ? 0x07060302u : 0x01000504u;
    const int mrow = 4 * lq + (l & 3);

    // hoisted, t-invariant A-read uint4-indices and Ew write dword-indices
    int aidx[8];
#pragma unroll
    for (int kt = 0; kt < 4; ++kt) {
#pragma unroll
        for (int c = 0; c < 2; ++c)
            aidx[kt * 2 + c] = lc * 32 + (((kt * 8 + lq * 2 + c) ^ lc) & 31);
    }
    int widx[4];
#pragma unroll
    for (int nt = 0; nt < 4; ++nt)
        widx[nt] = mrow * 128 + ((((w * 4 + nt) ^ mrow) & 31) << 2) + (lc >> 2);

    // A-row held by this lane is row lc -> batch bA = lc>>2.
    const int bA = lc >> 2;
    const int h  = lq >> 1;                 // producer wave w' = 2*kt + h
    const int wexp_w = (w & 1) * 16 + lq * 4 + (w >> 1);   // my wmE2 byte slot
    const bool real = (l & 3) == 0;          // lane holds a real (nonzero) A-row

    __syncthreads();   // Ew zero-init visible before first masked writes

    const v4f CZ = {0.f, 0.f, 0.f, 0.f};

    // hoisted zero A fragments; masked-out lanes keep zeros forever
    v8i A[4];
#pragma unroll
    for (int kt = 0; kt < 4; ++kt)
#pragma unroll
        for (int i = 0; i < 8; ++i) A[kt][i] = 0;

    // ---- emission gather pipeline (depth 1) ----
    float gcur[4];
    int idB;
    {
        const int idA = idp[1];
#pragma unroll
        for (int nt = 0; nt < 4; ++nt) gcur[nt] = er[nt][idA];
        idB = idp[2];
    }

    for (int t = 1; t < NT; ++t) {
        const int buf = t & 1;
        unsigned* EwB = &Ew[buf][0];

        // ---- per-batch WAVE-LOCAL max (row of 16 = one batch) ----
        float mx = fmaxf(fmaxf(alpha[0], alpha[1]), fmaxf(alpha[2], alpha[3]));
        DPPMAX(mx, 0x128); DPPMAX(mx, 0x124); DPPMAX(mx, 0xB1); DPPMAX(mx, 0x4E);
        unsigned E = __float_as_uint(mx) >> 23;
        E = E > 1u ? E : 1u;
        const float sc = __uint_as_float((261u - E) << 23);   // 2^(134-E)

        // ---- e -> fp8 (LOCAL scale), DPP 4x4 byte transpose ----
        unsigned dwv[4];
#pragma unroll
        for (int nt = 0; nt < 4; ++nt) {
            unsigned dw = pack1_e4m3(alpha[nt] * sc);
            int tmp = __builtin_amdgcn_mov_dpp((int)dw, 0xB1, 0xF, 0xF, true);
            dw = __builtin_amdgcn_perm(dw, (unsigned)tmp, sel1);
            tmp = __builtin_amdgcn_mov_dpp((int)dw, 0x4E, 0xF, 0xF, true);
            dw = __builtin_amdgcn_perm(dw, (unsigned)tmp, sel2);
            dwv[nt] = dw;
        }
        if (real) {
#pragma unroll
            for (int nt = 0; nt < 4; ++nt) EwB[widx[nt]] = dwv[nt];
        }
        if (lc == 0) wmE2[buf][wexp_w] = (unsigned char)E;
        __syncthreads();                                    // the ONLY barrier

        // ---- (1) scale-exponent dwords FIRST (fresh, no lag) ----
        const unsigned dA0 = *(const unsigned*)&wmE2[buf][bA * 4];
        const unsigned dA1 = *(const unsigned*)&wmE2[buf][16 + bA * 4];
        const unsigned dQ0 = *(const unsigned*)&wmE2[buf][lq * 4];
        const unsigned dQ1 = *(const unsigned*)&wmE2[buf][16 + lq * 4];

        // ---- (2) issue NEXT step's emission gathers (full-step cover) ----
        float gnxt[4];
#pragma unroll
        for (int nt = 0; nt < 4; ++nt) gnxt[nt] = er[nt][idB];
        idB = idp[(t + 2) & 127];

        // ---- (3) A fragments from LDS (masked to real lanes) ----
        if (real) {
            const uint4* eb4 = (const uint4*)EwB;
#pragma unroll
            for (int kt = 0; kt < 4; ++kt) {
                *(uint4*)&A[kt]       = eb4[aidx[kt * 2 + 0]];
                *((uint4*)&A[kt] + 1) = eb4[aidx[kt * 2 + 1]];
            }
        }

        // ---- (4) scales (per-lane byte-max, v5 scheme) ----
        const unsigned MA = bytemax8(dA0, dA1);   // A-row batch reference
        const unsigned MQ = bytemax8(dQ0, dQ1);   // own batch -> gsum
        gsum += (int)MQ - 126;

        const unsigned dwE = h ? dA1 : dA0;       // my 4 per-kt exponents
        const int base = 127 - (int)MA;
        int s0 = (int)(dwE & 255u) + base;         s0 = s0 < 0 ? 0 : s0;
        int s1 = (int)((dwE >> 8) & 255u) + base;  s1 = s1 < 0 ? 0 : s1;
        int s2 = (int)((dwE >> 16) & 255u) + base; s2 = s2 < 0 ? 0 : s2;
        int s3 = (int)(dwE >> 24) + base;          s3 = s3 < 0 ? 0 : s3;
        const int scA[4] = { s0 * 0x01010101, s1 * 0x01010101,
                             s2 * 0x01010101, s3 * 0x01010101 };

        // ---- (5) MFMA: pairwise chains ----
        v4f Ca[4], Cb[4];
#pragma unroll
        for (int nt = 0; nt < 4; ++nt)
            Ca[nt] = __builtin_amdgcn_mfma_scale_f32_16x16x128_f8f6f4(
                         A[0], B[nt][0], CZ, 0, 0, 0, scA[0], 0, 0x7F7F7F7F);
#pragma unroll
        for (int nt = 0; nt < 4; ++nt)
            Ca[nt] = __builtin_amdgcn_mfma_scale_f32_16x16x128_f8f6f4(
                         A[1], B[nt][1], Ca[nt], 0, 0, 0, scA[1], 0, 0x7F7F7F7F);
#pragma unroll
        for (int nt = 0; nt < 4; ++nt)
            Cb[nt] = __builtin_amdgcn_mfma_scale_f32_16x16x128_f8f6f4(
                         A[2], B[nt][2], CZ, 0, 0, 0, scA[2], 0, 0x7F7F7F7F);
#pragma unroll
        for (int nt = 0; nt < 4; ++nt)
            Cb[nt] = __builtin_amdgcn_mfma_scale_f32_16x16x128_f8f6f4(
                         A[3], B[nt][3], Cb[nt], 0, 0, 0, scA[3], 0, 0x7F7F7F7F);

        // ---- (6) alpha update with THIS step's emission (gathered last iter) ----
#pragma unroll
        for (int nt = 0; nt < 4; ++nt)
            alpha[nt] = (Ca[nt][0] + Cb[nt][0]) * (__expf(gcur[nt]) * iz[nt]);
#pragma unroll
        for (int nt = 0; nt < 4; ++nt) gcur[nt] = gnxt[nt];
    }

    // ---- final: per-batch logsumexp over states ----
    {
        float sm = (alpha[0] + alpha[1]) + (alpha[2] + alpha[3]);
        DPPADD(sm, 0x128); DPPADD(sm, 0x124); DPPADD(sm, 0xB1); DPPADD(sm, 0x4E);
        if (lc == 0) wm2[w][lq] = sm;
        if (w == 0 && lc == 0) sbuf[lq] = (float)gsum;
    }
    __syncthreads();
    if (tid < 4) {
        float s8 = ((wm2[0][tid] + wm2[1][tid]) + (wm2[2][tid] + wm2[3][tid]))
                 + ((wm2[4][tid] + wm2[5][tid]) + (wm2[6][tid] + wm2[7][tid]));
        float L2 = __log2f(s8) + sbuf[tid];
        atomicAdd(out, -(0.693147180559945f / 16.0f) * L2);
    }
}

// ---------------------------------------------------------------------------
extern "C" void kernel_launch(void* const* d_in, const int* in_sizes, int n_in,
                              void* d_out, int out_size, void* d_ws, size_t ws_size,
                              hipStream_t stream)
{
    const int*   ids = (const int*)d_in[0];   // [16][128]
    const float* em  = (const float*)d_in[1]; // [512][32000]
    const float* tm  = (const float*)d_in[2]; // [512][512]
    const float* p   = (const float*)d_in[3]; // [512]
    float* out = (float*)d_out;

    float*          invZs = (float*)d_ws;                              // 2 KB
    unsigned char*  PT    = (unsigned char*)d_ws + ((size_t)64 << 10); // 256 KB

    hipMemsetAsync(d_out, 0, sizeof(float), stream);

    k_logz<<<NS, 256, 0, stream>>>(em, invZs);
    k_pt2f<<<8, 256, 0, stream>>>(tm, PT);
    k_scan<<<4, 512, 0, stream>>>(em, ids, invZs, PT, p, out);
}